// Round 1
// baseline (5494.242 us; speedup 1.0000x reference)
//
#include <hip/hip_runtime.h>
#include <cstdint>
#include <cstddef>

// Problem constants
#define kSEQ 100
#define kB   200
#define kNP  512
#define kNG  4096
#define kMP  256   // padded M for the recurrent/encoder GEMMs (4 tiles of 64... 2 tiles of 128)

typedef __bf16 bf16_t;
typedef bf16_t bf16x8 __attribute__((ext_vector_type(8)));
typedef float  f32x4  __attribute__((ext_vector_type(4)));

__device__ __forceinline__ unsigned short f2bf(float f) {
    unsigned int u = __builtin_bit_cast(unsigned int, f);
    unsigned int r = (u + 0x7FFFu + ((u >> 16) & 1u)) >> 16;
    return (unsigned short)r;
}
__device__ __forceinline__ float bf2f(unsigned short b) {
    unsigned int u = ((unsigned int)b) << 16;
    return __builtin_bit_cast(float, u);
}

// ---------------------------------------------------------------------------
// Split fp32 -> (hi, lo) bf16 pair.  n4 = number of float4 groups.
// ---------------------------------------------------------------------------
__global__ __launch_bounds__(256)
void k_split(const float* __restrict__ src, unsigned short* __restrict__ hi,
             unsigned short* __restrict__ lo, int n4) {
    int i = blockIdx.x * 256 + threadIdx.x;
    if (i >= n4) return;
    float4 v = ((const float4*)src)[i];
    ushort4 h, l;
    h.x = f2bf(v.x); l.x = f2bf(v.x - bf2f(h.x));
    h.y = f2bf(v.y); l.y = f2bf(v.y - bf2f(h.y));
    h.z = f2bf(v.z); l.z = f2bf(v.z - bf2f(h.z));
    h.w = f2bf(v.w); l.w = f2bf(v.w - bf2f(h.w));
    ((ushort4*)hi)[i] = h;
    ((ushort4*)lo)[i] = l;
}

// ---------------------------------------------------------------------------
// Split-precision bf16 MFMA GEMM:  part[ks][m][n] = sum_k A[m][k]*B[n][k]
// over this block's K-chunk.  A = (Ahi+Alo), B = (Bhi+Blo); 3 products.
// Grid: (N/128, kMP/128, KSPLIT).  256 threads, 4 waves of 64x64.
// N is fixed at kNG (both uses have N = 4096 output columns).
// ---------------------------------------------------------------------------
__global__ __launch_bounds__(256)
void k_gemm_split(const unsigned short* __restrict__ Ahi, const unsigned short* __restrict__ Alo, int lda,
                  const unsigned short* __restrict__ Bhi, const unsigned short* __restrict__ Blo, int ldb,
                  float* __restrict__ part, int kPerChunk) {
    __shared__ __align__(16) unsigned short sAh[128 * 64];
    __shared__ __align__(16) unsigned short sAl[128 * 64];
    __shared__ __align__(16) unsigned short sBh[128 * 64];
    __shared__ __align__(16) unsigned short sBl[128 * 64];

    const int tid  = threadIdx.x;
    const int lane = tid & 63;
    const int wid  = tid >> 6;
    const int wr   = wid >> 1;   // wave row (0..1)
    const int wc   = wid & 1;    // wave col (0..1)
    const int m0   = blockIdx.y * 128;
    const int n0   = blockIdx.x * 128;
    const int kBase = blockIdx.z * kPerChunk;

    f32x4 acc[4][4];
#pragma unroll
    for (int i = 0; i < 4; i++)
#pragma unroll
        for (int j = 0; j < 4; j++) acc[i][j] = (f32x4){0.f, 0.f, 0.f, 0.f};

    const int sr = tid >> 1;          // staging row 0..127
    const int sc = (tid & 1) * 32;    // staging col offset (bf16 elems)
    const unsigned int swzrow = ((unsigned)sr & 7u) << 4;
    const unsigned int sbase  = (unsigned)sr * 128u + (unsigned)(tid & 1) * 64u;

    for (int kb = 0; kb < kPerChunk; kb += 64) {
        const int k0 = kBase + kb;
        __syncthreads();
        {
            const uint4* gAh = (const uint4*)(Ahi + (size_t)(m0 + sr) * (size_t)lda + k0 + sc);
            const uint4* gAl = (const uint4*)(Alo + (size_t)(m0 + sr) * (size_t)lda + k0 + sc);
            const uint4* gBh = (const uint4*)(Bhi + (size_t)(n0 + sr) * (size_t)ldb + k0 + sc);
            const uint4* gBl = (const uint4*)(Blo + (size_t)(n0 + sr) * (size_t)ldb + k0 + sc);
#pragma unroll
            for (int i = 0; i < 4; i++) {
                unsigned int off = (sbase + (unsigned)i * 16u) ^ swzrow;
                *(uint4*)((char*)sAh + off) = gAh[i];
                *(uint4*)((char*)sAl + off) = gAl[i];
                *(uint4*)((char*)sBh + off) = gBh[i];
                *(uint4*)((char*)sBl + off) = gBl[i];
            }
        }
        __syncthreads();
#pragma unroll
        for (int ks2 = 0; ks2 < 2; ks2++) {
            bf16x8 ah[4], al[4], bh[4], bl[4];
            const unsigned int klane = (unsigned)(lane >> 4) * 16u + (unsigned)ks2 * 64u;
#pragma unroll
            for (int fm = 0; fm < 4; fm++) {
                const unsigned int row = (unsigned)(wr * 64 + fm * 16 + (lane & 15));
                const unsigned int off = (row * 128u + klane) ^ ((row & 7u) << 4);
                ah[fm] = *(const bf16x8*)((const char*)sAh + off);
                al[fm] = *(const bf16x8*)((const char*)sAl + off);
            }
#pragma unroll
            for (int fn = 0; fn < 4; fn++) {
                const unsigned int row = (unsigned)(wc * 64 + fn * 16 + (lane & 15));
                const unsigned int off = (row * 128u + klane) ^ ((row & 7u) << 4);
                bh[fn] = *(const bf16x8*)((const char*)sBh + off);
                bl[fn] = *(const bf16x8*)((const char*)sBl + off);
            }
#pragma unroll
            for (int fm = 0; fm < 4; fm++)
#pragma unroll
                for (int fn = 0; fn < 4; fn++) {
                    acc[fm][fn] = __builtin_amdgcn_mfma_f32_16x16x32_bf16(ah[fm], bh[fn], acc[fm][fn], 0, 0, 0);
                    acc[fm][fn] = __builtin_amdgcn_mfma_f32_16x16x32_bf16(ah[fm], bl[fn], acc[fm][fn], 0, 0, 0);
                    acc[fm][fn] = __builtin_amdgcn_mfma_f32_16x16x32_bf16(al[fm], bh[fn], acc[fm][fn], 0, 0, 0);
                }
        }
    }

    float* po = part + (size_t)blockIdx.z * ((size_t)kMP * kNG);
#pragma unroll
    for (int fm = 0; fm < 4; fm++)
#pragma unroll
        for (int fn = 0; fn < 4; fn++) {
            const int row0 = m0 + wr * 64 + fm * 16 + ((lane >> 4) << 2);
            const int col  = n0 + wc * 64 + fn * 16 + (lane & 15);
#pragma unroll
            for (int j = 0; j < 4; j++)
                po[(size_t)(row0 + j) * kNG + col] = acc[fm][fn][j];
        }
}

// ---------------------------------------------------------------------------
// Reduce 4 K-partials; mode 1: add velocity*W_ih^T, ReLU, store g (fp32) and
// next-h (bf16 hi/lo).  mode 0 (encoder): no vx/relu/g-store, just split h0.
// Grid: (4, kB), 256 threads, 4 g's per thread.
// ---------------------------------------------------------------------------
__global__ __launch_bounds__(256)
void k_reduce(const float* __restrict__ part,
              const float* __restrict__ velocity, const float* __restrict__ W_ih,
              float* __restrict__ gout,
              unsigned short* __restrict__ hhi, unsigned short* __restrict__ hlo,
              int t, int mode) {
    const int b = blockIdx.y;
    const int g = blockIdx.x * 1024 + threadIdx.x * 4;

    float4 s = *(const float4*)(part + (size_t)b * kNG + g);
    float v0 = s.x, v1 = s.y, v2 = s.z, v3 = s.w;
#pragma unroll
    for (int ks = 1; ks < 4; ks++) {
        float4 p = *(const float4*)(part + (size_t)ks * ((size_t)kMP * kNG) + (size_t)b * kNG + g);
        v0 += p.x; v1 += p.y; v2 += p.z; v3 += p.w;
    }
    if (mode == 1) {
        const float2 vel = *(const float2*)(velocity + ((size_t)t * kB + b) * 2);
        const float4 w01 = *(const float4*)(W_ih + (size_t)g * 2);
        const float4 w23 = *(const float4*)(W_ih + (size_t)g * 2 + 4);
        v0 = fmaxf(0.f, v0 + vel.x * w01.x + vel.y * w01.y);
        v1 = fmaxf(0.f, v1 + vel.x * w01.z + vel.y * w01.w);
        v2 = fmaxf(0.f, v2 + vel.x * w23.x + vel.y * w23.y);
        v3 = fmaxf(0.f, v3 + vel.x * w23.z + vel.y * w23.w);
        float4 o; o.x = v0; o.y = v1; o.z = v2; o.w = v3;
        *(float4*)(gout + ((size_t)t * kB + b) * kNG + g) = o;
    }
    ushort4 hh, hl;
    hh.x = f2bf(v0); hl.x = f2bf(v0 - bf2f(hh.x));
    hh.y = f2bf(v1); hl.y = f2bf(v1 - bf2f(hh.y));
    hh.z = f2bf(v2); hl.z = f2bf(v2 - bf2f(hh.z));
    hh.w = f2bf(v3); hl.w = f2bf(v3 - bf2f(hh.w));
    *(ushort4*)(hhi + (size_t)b * kNG + g) = hh;
    *(ushort4*)(hlo + (size_t)b * kNG + g) = hl;
}

// ---------------------------------------------------------------------------
// Decoder: logits[r][p] = sum_g G[r][g] * Wdec[p][g], single-bf16 MFMA.
// A (G) is fp32 in global, converted to bf16 during staging.
// Grid: (kNP/128, ceil(20000/128)), 256 threads, 4 waves of 64x64.
// ---------------------------------------------------------------------------
__global__ __launch_bounds__(256)
void k_dec(const float* __restrict__ G, const unsigned short* __restrict__ Bhi,
           float* __restrict__ out) {
    __shared__ __align__(16) unsigned short sA[128 * 64];
    __shared__ __align__(16) unsigned short sB[128 * 64];

    const int tid  = threadIdx.x;
    const int lane = tid & 63;
    const int wid  = tid >> 6;
    const int wr   = wid >> 1;
    const int wc   = wid & 1;
    const int m0   = blockIdx.y * 128;
    const int n0   = blockIdx.x * 128;
    const int M    = kSEQ * kB; // 20000

    f32x4 acc[4][4];
#pragma unroll
    for (int i = 0; i < 4; i++)
#pragma unroll
        for (int j = 0; j < 4; j++) acc[i][j] = (f32x4){0.f, 0.f, 0.f, 0.f};

    const int sr = tid >> 1;
    const int scf = (tid & 1) * 32;   // f32 col offset for A
    const unsigned int swzrow = ((unsigned)sr & 7u) << 4;
    int arow = m0 + sr; if (arow > M - 1) arow = M - 1;

    for (int k0 = 0; k0 < kNG; k0 += 64) {
        __syncthreads();
        {
            const float4* gA = (const float4*)(G + (size_t)arow * kNG + k0 + scf);
#pragma unroll
            for (int i = 0; i < 8; i++) {
                float4 vv = gA[i];
                ushort4 hv;
                hv.x = f2bf(vv.x); hv.y = f2bf(vv.y); hv.z = f2bf(vv.z); hv.w = f2bf(vv.w);
                unsigned int off = ((unsigned)sr * 128u + (unsigned)scf * 2u + (unsigned)i * 8u) ^ swzrow;
                *(ushort4*)((char*)sA + off) = hv;
            }
            const uint4* gB = (const uint4*)(Bhi + (size_t)(n0 + sr) * kNG + k0 + scf);
#pragma unroll
            for (int i = 0; i < 4; i++) {
                unsigned int off = ((unsigned)sr * 128u + (unsigned)(tid & 1) * 64u + (unsigned)i * 16u) ^ swzrow;
                *(uint4*)((char*)sB + off) = gB[i];
            }
        }
        __syncthreads();
#pragma unroll
        for (int ks2 = 0; ks2 < 2; ks2++) {
            bf16x8 a[4], bfr[4];
            const unsigned int klane = (unsigned)(lane >> 4) * 16u + (unsigned)ks2 * 64u;
#pragma unroll
            for (int fm = 0; fm < 4; fm++) {
                const unsigned int row = (unsigned)(wr * 64 + fm * 16 + (lane & 15));
                const unsigned int off = (row * 128u + klane) ^ ((row & 7u) << 4);
                a[fm] = *(const bf16x8*)((const char*)sA + off);
            }
#pragma unroll
            for (int fn = 0; fn < 4; fn++) {
                const unsigned int row = (unsigned)(wc * 64 + fn * 16 + (lane & 15));
                const unsigned int off = (row * 128u + klane) ^ ((row & 7u) << 4);
                bfr[fn] = *(const bf16x8*)((const char*)sB + off);
            }
#pragma unroll
            for (int fm = 0; fm < 4; fm++)
#pragma unroll
                for (int fn = 0; fn < 4; fn++)
                    acc[fm][fn] = __builtin_amdgcn_mfma_f32_16x16x32_bf16(a[fm], bfr[fn], acc[fm][fn], 0, 0, 0);
        }
    }

#pragma unroll
    for (int fm = 0; fm < 4; fm++)
#pragma unroll
        for (int fn = 0; fn < 4; fn++) {
            const int row0 = m0 + wr * 64 + fm * 16 + ((lane >> 4) << 2);
            const int col  = n0 + wc * 64 + fn * 16 + (lane & 15);
#pragma unroll
            for (int j = 0; j < 4; j++) {
                const int row = row0 + j;
                if (row < M) out[(size_t)row * kNP + col] = acc[fm][fn][j];
            }
        }
}

// ---------------------------------------------------------------------------
extern "C" void kernel_launch(void* const* d_in, const int* in_sizes, int n_in,
                              void* d_out, int out_size, void* d_ws, size_t ws_size,
                              hipStream_t stream) {
    const float* velocity = (const float*)d_in[0];
    const float* init_pc  = (const float*)d_in[1];
    const float* W_enc    = (const float*)d_in[2];
    const float* W_ih     = (const float*)d_in[3];
    const float* W_hh     = (const float*)d_in[4];
    const float* W_dec    = (const float*)d_in[5];

    float* logits = (float*)d_out;                         // (100,200,512)
    float* gout   = logits + (size_t)kSEQ * kB * kNP;      // (100,200,4096)

    char* ws = (char*)d_ws;
    size_t off = 0;
    auto alloc = [&](size_t bytes) -> void* {
        void* p = ws + off;
        off += (bytes + 255) & ~(size_t)255;
        return p;
    };
    unsigned short* whh_hi  = (unsigned short*)alloc((size_t)kNG * kNG * 2);
    unsigned short* whh_lo  = (unsigned short*)alloc((size_t)kNG * kNG * 2);
    unsigned short* wdec_hi = (unsigned short*)alloc((size_t)kNP * kNG * 2);
    unsigned short* wdec_lo = (unsigned short*)alloc((size_t)kNP * kNG * 2);
    unsigned short* wenc_hi = (unsigned short*)alloc((size_t)kNG * kNP * 2);
    unsigned short* wenc_lo = (unsigned short*)alloc((size_t)kNG * kNP * 2);
    unsigned short* ip_hi   = (unsigned short*)alloc((size_t)kMP * kNP * 2);
    unsigned short* ip_lo   = (unsigned short*)alloc((size_t)kMP * kNP * 2);
    unsigned short* h_hi[2], *h_lo[2];
    h_hi[0] = (unsigned short*)alloc((size_t)kMP * kNG * 2);
    h_lo[0] = (unsigned short*)alloc((size_t)kMP * kNG * 2);
    h_hi[1] = (unsigned short*)alloc((size_t)kMP * kNG * 2);
    h_lo[1] = (unsigned short*)alloc((size_t)kMP * kNG * 2);
    float* partial = (float*)alloc((size_t)4 * kMP * kNG * 4);

    // --- pre-split weights / initial state ---
    int n4;
    n4 = kNG * kNG / 4;
    k_split<<<(n4 + 255) / 256, 256, 0, stream>>>(W_hh, whh_hi, whh_lo, n4);
    n4 = kNP * kNG / 4;
    k_split<<<(n4 + 255) / 256, 256, 0, stream>>>(W_dec, wdec_hi, wdec_lo, n4);
    n4 = kNG * kNP / 4;
    k_split<<<(n4 + 255) / 256, 256, 0, stream>>>(W_enc, wenc_hi, wenc_lo, n4);
    n4 = kB * kNP / 4;
    k_split<<<(n4 + 255) / 256, 256, 0, stream>>>(init_pc, ip_hi, ip_lo, n4);

    dim3 gG(kNG / 128, kMP / 128, 4);   // (32, 2, 4)
    dim3 gR(4, kB);

    // --- encoder: h0 = init_pc @ W_enc^T ---
    k_gemm_split<<<gG, 256, 0, stream>>>(ip_hi, ip_lo, kNP, wenc_hi, wenc_lo, kNP, partial, kNP / 4);
    k_reduce<<<gR, 256, 0, stream>>>(partial, velocity, W_ih, nullptr, h_hi[0], h_lo[0], 0, 0);

    // --- recurrent scan ---
    int p = 0;
    for (int t = 0; t < kSEQ; t++) {
        k_gemm_split<<<gG, 256, 0, stream>>>(h_hi[p], h_lo[p], kNG, whh_hi, whh_lo, kNG, partial, kNG / 4);
        k_reduce<<<gR, 256, 0, stream>>>(partial, velocity, W_ih, gout, h_hi[p ^ 1], h_lo[p ^ 1], t, 1);
        p ^= 1;
    }

    // --- decoder ---
    dim3 gD(kNP / 128, (kSEQ * kB + 127) / 128);   // (4, 157)
    k_dec<<<gD, 256, 0, stream>>>(gout, wdec_hi, logits);
}